// Round 1
// baseline (20.676 us; speedup 1.0000x reference)
//
#include <hip/hip_runtime.h>
#include <math.h>

#define BLOCK 256

__device__ __forceinline__ void walker_accum(
    float x0, float y0, float z0, float x1, float y1, float z1,
    float Z, float k1, float k2,
    float c1r, float c1i, float c2r, float c2i,
    double& s_hr, double& s_hi, double& s_pr, double& s_pi)
{
    float r0 = sqrtf(x0*x0 + y0*y0 + z0*z0);
    float r1 = sqrtf(x1*x1 + y1*y1 + z1*z1);
    float ir0 = 1.0f / r0;
    float ir1 = 1.0f / r1;

    // exp(-Z r) = h^2 with h = exp(-0.5 Z r): one expf per particle
    float h0 = expf(-0.5f * Z * r0);
    float h1 = expf(-0.5f * Z * r1);
    float e0 = h0 * h0;
    float e1 = h1 * h1;

    float psi1_0 = k1 * e0;
    float psi1_1 = k1 * e1;
    float psi2_0 = k2 * (2.0f - Z * r0) * h0;
    float psi2_1 = k2 * (2.0f - Z * r1) * h1;

    float Psi1 = psi1_0 * psi1_1;
    float Psi2 = psi2_0 * psi2_1;

    float sum_inv = ir0 + ir1;
    float lap1 = 2.0f   * Z * Z - 2.0f * Z * sum_inv;   // n=1, two particles
    float lap2 = 0.5f   * Z * Z - 2.0f * Z * sum_inv;   // n=2 (0.25 Z^2 each)

    float dx = x0 - x1, dy = y0 - y1, dz = z0 - z1;
    float d12 = sqrtf(dx*dx + dy*dy + dz*dz);
    float V = -1.0f / d12;                               // VB = 1

    float H1 = (-0.5f * lap1 + V) * Psi1;
    float H2 = (-0.5f * lap2 + V) * Psi2;

    // H_psi = c1*H1 + c2*H2 ; psi = c1*Psi1 + c2*Psi2 ; psistar = conj
    float Hr = c1r * H1 + c2r * H2;
    float Hi = c1i * H1 + c2i * H2;
    float Pr = c1r * Psi1 + c2r * Psi2;
    float Pi = c1i * Psi1 + c2i * Psi2;
    float Sr = Pr;
    float Si = -Pi;

    // hammy = psistar * H_psi ; psi2 = psistar * psi
    s_hr += (double)(Sr * Hr - Si * Hi);
    s_hi += (double)(Sr * Hi + Si * Hr);
    s_pr += (double)(Sr * Pr - Si * Pi);
    s_pi += (double)(Sr * Pi + Si * Pr);
}

__global__ __launch_bounds__(BLOCK) void wvfn_partial(
    const float4* __restrict__ Rs4,   // [npairs*3] float4 view of [N,2,3] f32
    const float* __restrict__ a_p,
    const float* __restrict__ c1r_p, const float* __restrict__ c1i_p,
    const float* __restrict__ c2r_p, const float* __restrict__ c2i_p,
    double* __restrict__ partials,    // [gridDim.x * 4]
    int npairs)
{
    const float Z   = 1.0f / a_p[0];
    const float c1r = c1r_p[0], c1i = c1i_p[0];
    const float c2r = c2r_p[0], c2i = c2i_p[0];
    const float Y00 = 0.28209479177387814f;      // 1/sqrt(4*pi)
    const float Zs  = Z * sqrtf(Z);              // Z^1.5
    const float k1  = 2.0f * Zs * Y00;
    const float k2  = Zs * 0.3535533905932738f * Y00;  // 1/(2*sqrt(2))

    double s0 = 0.0, s1 = 0.0, s2 = 0.0, s3 = 0.0;

    int tid    = blockIdx.x * BLOCK + threadIdx.x;
    int stride = gridDim.x * BLOCK;
    for (int j = tid; j < npairs; j += stride) {
        float4 v0 = Rs4[3*j + 0];
        float4 v1 = Rs4[3*j + 1];
        float4 v2 = Rs4[3*j + 2];
        // walker 2j  : (v0.x v0.y v0.z | v0.w v1.x v1.y)
        // walker 2j+1: (v1.z v1.w v2.x | v2.y v2.z v2.w)
        walker_accum(v0.x, v0.y, v0.z, v0.w, v1.x, v1.y,
                     Z, k1, k2, c1r, c1i, c2r, c2i, s0, s1, s2, s3);
        walker_accum(v1.z, v1.w, v2.x, v2.y, v2.z, v2.w,
                     Z, k1, k2, c1r, c1i, c2r, c2i, s0, s1, s2, s3);
    }

    // wave(64) butterfly reduce
    for (int off = 32; off > 0; off >>= 1) {
        s0 += __shfl_down(s0, off);
        s1 += __shfl_down(s1, off);
        s2 += __shfl_down(s2, off);
        s3 += __shfl_down(s3, off);
    }

    __shared__ double sm[4][BLOCK / 64];
    int wid  = threadIdx.x >> 6;
    int lane = threadIdx.x & 63;
    if (lane == 0) { sm[0][wid] = s0; sm[1][wid] = s1; sm[2][wid] = s2; sm[3][wid] = s3; }
    __syncthreads();
    if (threadIdx.x == 0) {
        double t0 = 0, t1 = 0, t2 = 0, t3 = 0;
        for (int w = 0; w < BLOCK / 64; ++w) {
            t0 += sm[0][w]; t1 += sm[1][w]; t2 += sm[2][w]; t3 += sm[3][w];
        }
        partials[blockIdx.x * 4 + 0] = t0;
        partials[blockIdx.x * 4 + 1] = t1;
        partials[blockIdx.x * 4 + 2] = t2;
        partials[blockIdx.x * 4 + 3] = t3;
    }
}

__global__ __launch_bounds__(BLOCK) void wvfn_finish(
    const double* __restrict__ partials, int nblocks,
    float* __restrict__ out, int out_size)
{
    double s0 = 0, s1 = 0, s2 = 0, s3 = 0;
    for (int j = threadIdx.x; j < nblocks; j += BLOCK) {
        s0 += partials[4*j + 0];
        s1 += partials[4*j + 1];
        s2 += partials[4*j + 2];
        s3 += partials[4*j + 3];
    }
    for (int off = 32; off > 0; off >>= 1) {
        s0 += __shfl_down(s0, off);
        s1 += __shfl_down(s1, off);
        s2 += __shfl_down(s2, off);
        s3 += __shfl_down(s3, off);
    }
    __shared__ double sm[4][BLOCK / 64];
    int wid  = threadIdx.x >> 6;
    int lane = threadIdx.x & 63;
    if (lane == 0) { sm[0][wid] = s0; sm[1][wid] = s1; sm[2][wid] = s2; sm[3][wid] = s3; }
    __syncthreads();
    if (threadIdx.x == 0) {
        double t0 = 0, t1 = 0, t2 = 0, t3 = 0;
        for (int w = 0; w < BLOCK / 64; ++w) {
            t0 += sm[0][w]; t1 += sm[1][w]; t2 += sm[2][w]; t3 += sm[3][w];
        }
        // result = (t0 + i t1) / (t2 + i t3)   (the 1/N mean factors cancel)
        double den = t2 * t2 + t3 * t3;
        double rr  = (t0 * t2 + t1 * t3) / den;
        double ri  = (t1 * t2 - t0 * t3) / den;
        out[0] = (float)rr;
        if (out_size > 1) out[1] = (float)ri;
    }
}

extern "C" void kernel_launch(void* const* d_in, const int* in_sizes, int n_in,
                              void* d_out, int out_size, void* d_ws, size_t ws_size,
                              hipStream_t stream) {
    const float4* Rs4 = (const float4*)d_in[0];
    const float* a_p  = (const float*)d_in[1];
    const float* c1r  = (const float*)d_in[2];
    const float* c1i  = (const float*)d_in[3];
    const float* c2r  = (const float*)d_in[4];
    const float* c2i  = (const float*)d_in[5];

    int N      = in_sizes[0] / 6;   // [N,2,3] f32 -> N walkers (N even here)
    int npairs = N / 2;

    int blocks = 1024;
    size_t need = (size_t)blocks * 4 * sizeof(double);
    if (need > ws_size) {
        blocks = (int)(ws_size / (4 * sizeof(double)));
        if (blocks < 1) blocks = 1;
    }

    double* partials = (double*)d_ws;
    wvfn_partial<<<blocks, BLOCK, 0, stream>>>(Rs4, a_p, c1r, c1i, c2r, c2i,
                                               partials, npairs);
    wvfn_finish<<<1, BLOCK, 0, stream>>>(partials, blocks, (float*)d_out, out_size);
}